// Round 5
// baseline (1877.106 us; speedup 1.0000x reference)
//
#include <hip/hip_runtime.h>
#include <math.h>

constexpr int HD  = 128;     // hidden
constexpr int FNN = 6;       // node in-features
constexpr int FEE = 3;       // edge in-features
constexpr int NN  = 40000;   // nodes per chunk
constexpr int EE  = 240000;  // edges
constexpr int SS  = 4;       // mp steps

typedef __bf16 bf16_t;
typedef bf16_t bf16x8 __attribute__((ext_vector_type(8)));
typedef bf16_t bf16x2 __attribute__((ext_vector_type(2)));
typedef float  f32x4  __attribute__((ext_vector_type(4)));

__device__ __forceinline__ f32x4 mfma16(bf16x8 a, bf16x8 b, f32x4 c){
  return __builtin_amdgcn_mfma_f32_16x16x32_bf16(a, b, c, 0, 0, 0);
}
// fast ELU: exp(v)-1 via v_exp_f32; abs err ~1e-7, invisible after bf16 round
__device__ __forceinline__ float elu(float v){ return v > 0.f ? v : __expf(v) - 1.f; }

// ---------------------------------------------------------------- weight pack
// Packed B-fragment layout per matrix (K padded to mult of 32):
//   flat = ((kt*4 + g)*128 + c)*8 + j   <->   element W[kt*32 + g*8 + j][c]
struct PackJob { const float* src; int K; };
struct PackArgs { PackJob j[22]; };

__global__ void __launch_bounds__(256) k_pack(PackArgs pa, bf16_t* __restrict__ dst){
  int gid = blockIdx.x*256 + threadIdx.x;
  int base = 0;
  #pragma unroll 1
  for (int i = 0; i < 22; ++i){
    int Kp = (pa.j[i].K + 31) & ~31;
    int sz = Kp * HD;
    if (gid < base + sz){
      int idx = gid - base;
      int jj = idx & 7, c = (idx >> 3) & 127, gi = idx >> 10;
      int g = gi & 3, kt = gi >> 2;
      int k = kt*32 + g*8 + jj;
      float v = (k < pa.j[i].K) ? pa.j[i].src[(size_t)k*HD + c] : 0.f;
      dst[base + idx] = (bf16_t)v;
      return;
    }
    base += sz;
  }
}

// ---------------------------------------------------------------- CSR build
__global__ void k_cnt(const int* __restrict__ ei1, int* __restrict__ cnt){
  int t = blockIdx.x*blockDim.x + threadIdx.x;
  if (t < EE) atomicAdd(cnt + ei1[t], 1);
}

__global__ void __launch_bounds__(1024) k_scan(const int* __restrict__ cnt,
    int* __restrict__ rowstart, int* __restrict__ cursor, float* __restrict__ inv){
  __shared__ int sdata[1024];
  __shared__ int carry_s;
  if (threadIdx.x == 0) carry_s = 0;
  __syncthreads();
  for (int base = 0; base < NN; base += 1024){
    int i = base + (int)threadIdx.x;
    int orig = (i < NN) ? cnt[i] : 0;
    sdata[threadIdx.x] = orig;
    __syncthreads();
    #pragma unroll
    for (int ofs = 1; ofs < 1024; ofs <<= 1){
      int t = (threadIdx.x >= (unsigned)ofs) ? sdata[threadIdx.x - ofs] : 0;
      __syncthreads();
      sdata[threadIdx.x] += t;
      __syncthreads();
    }
    int incl = sdata[threadIdx.x];
    int carry = carry_s;
    if (i < NN){
      int start = carry + incl - orig;
      rowstart[i] = start;
      cursor[i]   = start;
      inv[i] = 1.f / fmaxf((float)orig, 1.f);
    }
    __syncthreads();
    if (threadIdx.x == 1023) carry_s = carry + incl;
    __syncthreads();
  }
  if (threadIdx.x == 0) rowstart[NN] = carry_s;
}

__global__ void k_fill(const int* __restrict__ ei0, const int* __restrict__ ei1,
                       int* __restrict__ cursor, int* __restrict__ perm,
                       int* __restrict__ ei0p, int* __restrict__ ei1p){
  int t = blockIdx.x*blockDim.x + threadIdx.x;
  if (t < EE){
    int n1 = ei1[t];
    int pos = atomicAdd(cursor + n1, 1);
    perm[pos] = t;
    ei0p[pos] = ei0[t];
    ei1p[pos] = n1;
  }
}

// ---------------------------------------------------------------- segment-sum agg
// edges target-sorted; one wave per node; bf16 in, f32 accum, bf16 out (x inv fused)
__global__ void __launch_bounds__(256) k_agg(const bf16_t* __restrict__ e,
    const int* __restrict__ rowstart, const float* __restrict__ inv,
    bf16_t* __restrict__ agg){
  int node = (blockIdx.x*256 + (int)threadIdx.x) >> 6;
  int l = threadIdx.x & 63;
  if (node >= NN) return;
  int s = rowstart[node], t = rowstart[node+1];
  float a0 = 0.f, a1 = 0.f;
  for (int ed = s; ed < t; ++ed){
    bf16x2 v = *(const bf16x2*)(e + (size_t)ed*HD + l*2);
    a0 += (float)v[0]; a1 += (float)v[1];
  }
  float sc = inv[node];
  bf16x2 o; o[0] = (bf16_t)(a0*sc); o[1] = (bf16_t)(a1*sc);
  *(bf16x2*)(agg + (size_t)node*HD + l*2) = o;
}

// ---------------------------------------------------------------- encoder
// 3-layer MLP (scalar K=FIN layer, then 2 MFMA layers) + LayerNorm.
// Always writes bf16 outb; if ISNODE also writes fp32 outf.
// If perm != nullptr, input row `row` is read from xin[perm[row]] (edge case).
template<int FIN, bool ISNODE>
__global__ void __launch_bounds__(256) k_encoder(
    const float* __restrict__ xin, const float* __restrict__ mv, const float* __restrict__ sv,
    const float* __restrict__ w0,  const float* __restrict__ b0,
    const bf16_t* __restrict__ W1p, const float* __restrict__ b1,
    const bf16_t* __restrict__ W2p, const float* __restrict__ b2,
    const float* __restrict__ gg,  const float* __restrict__ bb,
    float* __restrict__ outf, bf16_t* __restrict__ outb,
    const int* __restrict__ perm)
{
  __shared__ bf16_t z0s[4][16][136];
  __shared__ bf16_t z1s[4][16][136];
  const int tid = threadIdx.x;
  const int w = tid >> 6, l = tid & 63, r = l & 15, grp = l >> 4;
  const int rowbase = blockIdx.x*64 + w*16;
  const int row = rowbase + r;
  const int src = perm ? perm[row] : row;

  float xn[FIN];
  #pragma unroll
  for (int f = 0; f < FIN; ++f) xn[f] = (xin[(size_t)src*FIN + f] - mv[f]) / sv[f];
  #pragma unroll
  for (int q = 0; q < 32; ++q){
    int c = grp*32 + q;
    float a = b0[c];
    #pragma unroll
    for (int f = 0; f < FIN; ++f) a += xn[f] * w0[f*HD + c];
    z0s[w][r][c] = (bf16_t)elu(a);
  }
  __syncthreads();

  bf16x8 a1[4];
  #pragma unroll
  for (int kt = 0; kt < 4; ++kt) a1[kt] = *(const bf16x8*)&z0s[w][r][kt*32 + grp*8];
  #pragma unroll
  for (int nt = 0; nt < 8; ++nt){
    int c = nt*16 + r;
    float bv = b1[c];
    f32x4 acc = {bv, bv, bv, bv};
    #pragma unroll
    for (int kt = 0; kt < 4; ++kt){
      bf16x8 bfr = *(const bf16x8*)(W1p + ((kt*4 + grp)*HD + c)*8);
      acc = mfma16(a1[kt], bfr, acc);
    }
    #pragma unroll
    for (int i = 0; i < 4; ++i) z1s[w][grp*4 + i][c] = (bf16_t)elu(acc[i]);
  }
  __syncthreads();

  bf16x8 a2[4];
  #pragma unroll
  for (int kt = 0; kt < 4; ++kt) a2[kt] = *(const bf16x8*)&z1s[w][r][kt*32 + grp*8];
  f32x4 et[8];
  #pragma unroll
  for (int nt = 0; nt < 8; ++nt){
    int c = nt*16 + r;
    float bv = b2[c];
    f32x4 acc = {bv, bv, bv, bv};
    #pragma unroll
    for (int kt = 0; kt < 4; ++kt){
      bf16x8 bfr = *(const bf16x8*)(W2p + ((kt*4 + grp)*HD + c)*8);
      acc = mfma16(a2[kt], bfr, acc);
    }
    et[nt] = acc;
  }

  f32x4 s = {0,0,0,0}, sq = {0,0,0,0};
  #pragma unroll
  for (int nt = 0; nt < 8; ++nt)
    #pragma unroll
    for (int i = 0; i < 4; ++i){ float v = et[nt][i]; s[i] += v; sq[i] += v*v; }
  #pragma unroll
  for (int m = 1; m < 16; m <<= 1)
    #pragma unroll
    for (int i = 0; i < 4; ++i){ s[i] += __shfl_xor(s[i], m, 64); sq[i] += __shfl_xor(sq[i], m, 64); }
  f32x4 mean, rstd;
  #pragma unroll
  for (int i = 0; i < 4; ++i){
    float mu = s[i] * (1.f/HD);
    float va = sq[i] * (1.f/HD) - mu*mu;
    mean[i] = mu; rstd[i] = rsqrtf(va + 1e-5f);
  }
  #pragma unroll
  for (int nt = 0; nt < 8; ++nt){
    int c = nt*16 + r;
    float gv = gg[c], bv = bb[c];
    #pragma unroll
    for (int i = 0; i < 4; ++i){
      float o = (et[nt][i] - mean[i]) * rstd[i] * gv + bv;
      size_t oidx = (size_t)(rowbase + grp*4 + i)*HD + c;
      outb[oidx] = (bf16_t)o;
      if constexpr (ISNODE) outf[oidx] = o;
    }
  }
}

// ---------------------------------------------------------------- edge MLP step
// e = LN(e + MLP2(ELU(MLP1(concat[h[ei0], h[ei1], e]))))   (in-place, bf16 e)
// 4 waves/block, 32 rows/wave (two 16-row MFMA tiles) -> each B-fragment feeds
// 2 MFMAs, halving the per-dispatch L2 weight stream (1.97 GB -> 0.98 GB).
__global__ void __launch_bounds__(256, 3) k_edge_mlp(
    const bf16_t* __restrict__ hbf, bf16_t* e_cur,
    const bf16_t* __restrict__ W0p, const float* __restrict__ b0,
    const bf16_t* __restrict__ W1p, const float* __restrict__ b1,
    const float* __restrict__ gg,  const float* __restrict__ bb,
    const int* __restrict__ ei0, const int* __restrict__ ei1)
{
  __shared__ bf16_t z1s[4][2][16][136];
  const int tid = threadIdx.x;
  const int w = tid >> 6, l = tid & 63, r = l & 15, grp = l >> 4;
  const int wavebase = blockIdx.x*128 + w*32;
  const int rowA = wavebase + r, rowB = rowA + 16;
  const int n0a = ei0[rowA], n0b = ei0[rowB];
  const int n1a = ei1[rowA], n1b = ei1[rowB];

  const bf16_t* srcA0 = hbf + (size_t)n0a*HD;
  const bf16_t* srcA1 = hbf + (size_t)n1a*HD;
  const bf16_t* srcA2 = e_cur + (size_t)rowA*HD;
  const bf16_t* srcB0 = hbf + (size_t)n0b*HD;
  const bf16_t* srcB1 = hbf + (size_t)n1b*HD;
  const bf16_t* srcB2 = e_cur + (size_t)rowB*HD;

  f32x4 acc[2][8];
  #pragma unroll
  for (int nt = 0; nt < 8; ++nt){
    float bv = b0[nt*16 + r];
    acc[0][nt] = {bv,bv,bv,bv};
    acc[1][nt] = {bv,bv,bv,bv};
  }
  #pragma unroll
  for (int kt = 0; kt < 12; ++kt){
    const int kk = (kt & 3)*32 + grp*8;
    const bf16_t* pa0 = (kt < 4) ? srcA0 : (kt < 8) ? srcA1 : srcA2;
    const bf16_t* pa1 = (kt < 4) ? srcB0 : (kt < 8) ? srcB1 : srcB2;
    bf16x8 a0 = *(const bf16x8*)(pa0 + kk);
    bf16x8 a1 = *(const bf16x8*)(pa1 + kk);
    #pragma unroll
    for (int nt = 0; nt < 8; ++nt){
      bf16x8 bfr = *(const bf16x8*)(W0p + ((kt*4 + grp)*HD + nt*16 + r)*8);
      acc[0][nt] = mfma16(a0, bfr, acc[0][nt]);
      acc[1][nt] = mfma16(a1, bfr, acc[1][nt]);
    }
  }
  #pragma unroll
  for (int nt = 0; nt < 8; ++nt){
    int c = nt*16 + r;
    #pragma unroll
    for (int i = 0; i < 4; ++i){
      z1s[w][0][grp*4 + i][c] = (bf16_t)elu(acc[0][nt][i]);
      z1s[w][1][grp*4 + i][c] = (bf16_t)elu(acc[1][nt][i]);
    }
  }
  __syncthreads();

  #pragma unroll
  for (int nt = 0; nt < 8; ++nt){
    float bv = b1[nt*16 + r];
    acc[0][nt] = {bv,bv,bv,bv};
    acc[1][nt] = {bv,bv,bv,bv};
  }
  #pragma unroll
  for (int kt = 0; kt < 4; ++kt){
    bf16x8 a0 = *(const bf16x8*)&z1s[w][0][r][kt*32 + grp*8];
    bf16x8 a1 = *(const bf16x8*)&z1s[w][1][r][kt*32 + grp*8];
    #pragma unroll
    for (int nt = 0; nt < 8; ++nt){
      bf16x8 bfr = *(const bf16x8*)(W1p + ((kt*4 + grp)*HD + nt*16 + r)*8);
      acc[0][nt] = mfma16(a0, bfr, acc[0][nt]);
      acc[1][nt] = mfma16(a1, bfr, acc[1][nt]);
    }
  }

  // residual + LN, per tile; lane owns rows wavebase + t*16 + grp*4 + i, col c
  #pragma unroll
  for (int t = 0; t < 2; ++t){
    f32x4 s = {0,0,0,0}, sq = {0,0,0,0};
    #pragma unroll
    for (int nt = 0; nt < 8; ++nt){
      int c = nt*16 + r;
      #pragma unroll
      for (int i = 0; i < 4; ++i){
        float v = acc[t][nt][i] + (float)e_cur[(size_t)(wavebase + t*16 + grp*4 + i)*HD + c];
        acc[t][nt][i] = v; s[i] += v; sq[i] += v*v;
      }
    }
    #pragma unroll
    for (int m = 1; m < 16; m <<= 1)
      #pragma unroll
      for (int i = 0; i < 4; ++i){ s[i] += __shfl_xor(s[i], m, 64); sq[i] += __shfl_xor(sq[i], m, 64); }
    f32x4 mean, rstd;
    #pragma unroll
    for (int i = 0; i < 4; ++i){
      float mu = s[i] * (1.f/HD);
      float va = sq[i] * (1.f/HD) - mu*mu;
      mean[i] = mu; rstd[i] = rsqrtf(va + 1e-5f);
    }
    #pragma unroll
    for (int nt = 0; nt < 8; ++nt){
      int c = nt*16 + r;
      float gv = gg[c], bv = bb[c];
      #pragma unroll
      for (int i = 0; i < 4; ++i)
        e_cur[(size_t)(wavebase + t*16 + grp*4 + i)*HD + c] =
            (bf16_t)((acc[t][nt][i] - mean[i]) * rstd[i] * gv + bv);
    }
  }
}

// ---------------------------------------------------------------- node MLP step
// h = LN(h + MLP2(ELU(MLP1(concat[h, agg]))));  agg is bf16, pre-scaled by 1/cnt
__global__ void __launch_bounds__(256) k_node_mlp(
    bf16_t* hbf, const bf16_t* __restrict__ agg,
    const bf16_t* __restrict__ W0p, const float* __restrict__ b0,
    const bf16_t* __restrict__ W1p, const float* __restrict__ b1,
    const float* __restrict__ gg,  const float* __restrict__ bb,
    float* hout)
{
  __shared__ bf16_t z1s[4][16][136];
  const int tid = threadIdx.x;
  const int w = tid >> 6, l = tid & 63, r = l & 15, grp = l >> 4;
  const int rowbase = blockIdx.x*64 + w*16;
  const int row = rowbase + r;

  bf16x8 afr[8];
  #pragma unroll
  for (int kt = 0; kt < 4; ++kt)
    afr[kt] = *(const bf16x8*)(hbf + (size_t)row*HD + kt*32 + grp*8);
  #pragma unroll
  for (int kt = 0; kt < 4; ++kt)
    afr[4+kt] = *(const bf16x8*)(agg + (size_t)row*HD + kt*32 + grp*8);

  #pragma unroll
  for (int nt = 0; nt < 8; ++nt){
    int c = nt*16 + r;
    float bv = b0[c];
    f32x4 acc = {bv, bv, bv, bv};
    #pragma unroll
    for (int kt = 0; kt < 8; ++kt){
      bf16x8 bfr = *(const bf16x8*)(W0p + ((kt*4 + grp)*HD + c)*8);
      acc = mfma16(afr[kt], bfr, acc);
    }
    #pragma unroll
    for (int i = 0; i < 4; ++i) z1s[w][grp*4 + i][c] = (bf16_t)elu(acc[i]);
  }
  __syncthreads();

  bf16x8 a2[4];
  #pragma unroll
  for (int kt = 0; kt < 4; ++kt) a2[kt] = *(const bf16x8*)&z1s[w][r][kt*32 + grp*8];
  f32x4 et[8];
  #pragma unroll
  for (int nt = 0; nt < 8; ++nt){
    int c = nt*16 + r;
    float bv = b1[c];
    f32x4 acc = {bv, bv, bv, bv};
    #pragma unroll
    for (int kt = 0; kt < 4; ++kt){
      bf16x8 bfr = *(const bf16x8*)(W1p + ((kt*4 + grp)*HD + c)*8);
      acc = mfma16(a2[kt], bfr, acc);
    }
    et[nt] = acc;
  }

  f32x4 s = {0,0,0,0}, sq = {0,0,0,0};
  #pragma unroll
  for (int nt = 0; nt < 8; ++nt){
    int c = nt*16 + r;
    #pragma unroll
    for (int i = 0; i < 4; ++i){
      float v = et[nt][i] + hout[(size_t)(rowbase + grp*4 + i)*HD + c];
      et[nt][i] = v; s[i] += v; sq[i] += v*v;
    }
  }
  #pragma unroll
  for (int m = 1; m < 16; m <<= 1)
    #pragma unroll
    for (int i = 0; i < 4; ++i){ s[i] += __shfl_xor(s[i], m, 64); sq[i] += __shfl_xor(sq[i], m, 64); }
  f32x4 mean, rstd;
  #pragma unroll
  for (int i = 0; i < 4; ++i){
    float mu = s[i] * (1.f/HD);
    float va = sq[i] * (1.f/HD) - mu*mu;
    mean[i] = mu; rstd[i] = rsqrtf(va + 1e-5f);
  }
  #pragma unroll
  for (int nt = 0; nt < 8; ++nt){
    int c = nt*16 + r;
    float gv = gg[c], bv = bb[c];
    #pragma unroll
    for (int i = 0; i < 4; ++i){
      float o = (et[nt][i] - mean[i]) * rstd[i] * gv + bv;
      size_t oidx = (size_t)(rowbase + grp*4 + i)*HD + c;
      hout[oidx] = o;
      hbf[oidx]  = (bf16_t)o;
    }
  }
}

// ---------------------------------------------------------------- host
extern "C" void kernel_launch(void* const* d_in, const int* in_sizes, int n_in,
                              void* d_out, int out_size, void* d_ws, size_t ws_size,
                              hipStream_t stream)
{
  (void)in_sizes; (void)n_in; (void)out_size; (void)ws_size;
  const float* x         = (const float*)d_in[0];
  const float* edge_attr = (const float*)d_in[1];
  const float* mvx = (const float*)d_in[2];
  const float* svx = (const float*)d_in[3];
  const float* mve = (const float*)d_in[4];
  const float* sve = (const float*)d_in[5];
  const float* nenc_w0 = (const float*)d_in[6];
  const float* nenc_b0 = (const float*)d_in[7];
  const float* nenc_w1 = (const float*)d_in[8];
  const float* nenc_b1 = (const float*)d_in[9];
  const float* nenc_w2 = (const float*)d_in[10];
  const float* nenc_b2 = (const float*)d_in[11];
  const float* nenc_g  = (const float*)d_in[12];
  const float* nenc_be = (const float*)d_in[13];
  const float* eenc_w0 = (const float*)d_in[14];
  const float* eenc_b0 = (const float*)d_in[15];
  const float* eenc_w1 = (const float*)d_in[16];
  const float* eenc_b1 = (const float*)d_in[17];
  const float* eenc_w2 = (const float*)d_in[18];
  const float* eenc_b2 = (const float*)d_in[19];
  const float* eenc_g  = (const float*)d_in[20];
  const float* eenc_be = (const float*)d_in[21];
  const float* emp_w0 = (const float*)d_in[22];
  const float* emp_b0 = (const float*)d_in[23];
  const float* emp_w1 = (const float*)d_in[24];
  const float* emp_b1 = (const float*)d_in[25];
  const float* emp_g  = (const float*)d_in[26];
  const float* emp_be = (const float*)d_in[27];
  const float* nmp_w0 = (const float*)d_in[28];
  const float* nmp_b0 = (const float*)d_in[29];
  const float* nmp_w1 = (const float*)d_in[30];
  const float* nmp_b1 = (const float*)d_in[31];
  const float* nmp_g  = (const float*)d_in[32];
  const float* nmp_be = (const float*)d_in[33];
  const int* eidx = (const int*)d_in[34];
  const int* ei0 = eidx;
  const int* ei1 = eidx + EE;
  float* out = (float*)d_out;

  // workspace carve-up (all 16B-aligned); total ~86 MB
  char* ws = (char*)d_ws;
  size_t off = 0;
  bf16_t* e_cur = (bf16_t*)(ws + off); off += (size_t)EE*HD*2;
  bf16_t* hbf   = (bf16_t*)(ws + off); off += (size_t)NN*HD*2;
  bf16_t* agg   = (bf16_t*)(ws + off); size_t agg_off = off; off += (size_t)NN*HD*2;
  float*  inv   = (float*)(ws + off);  off += (size_t)NN*4;
  int*    rowst = (int*)(ws + off);    off += (size_t)(NN+1)*4 + 12;  // keep 16B align
  int*    perm  = (int*)(ws + off);    off += (size_t)EE*4;
  int*    ei0p  = (int*)(ws + off);    off += (size_t)EE*4;
  int*    ei1p  = (int*)(ws + off);    off += (size_t)EE*4;
  bf16_t* wpk   = (bf16_t*)(ws + off);
  // CSR build scratch lives inside agg (only used before first k_agg)
  int*    cnt_i = (int*)(ws + agg_off);
  int*    curs  = (int*)(ws + agg_off + (size_t)NN*4);

  // ---- CSR build (target-sorted edge permutation)
  hipMemsetAsync(cnt_i, 0, NN*sizeof(int), stream);
  k_cnt<<<(EE + 255)/256, 256, 0, stream>>>(ei1, cnt_i);
  k_scan<<<1, 1024, 0, stream>>>(cnt_i, rowst, curs, inv);
  k_fill<<<(EE + 255)/256, 256, 0, stream>>>(ei0, ei1, curs, perm, ei0p, ei1p);

  // ---- weight packing
  PackArgs pa;
  const float* srcs[22] = {
    eenc_w0, eenc_w1, eenc_w2, nenc_w0, nenc_w1, nenc_w2,
    emp_w0, emp_w0 + 49152, emp_w0 + 2*49152, emp_w0 + 3*49152,
    emp_w1, emp_w1 + 16384, emp_w1 + 2*16384, emp_w1 + 3*16384,
    nmp_w0, nmp_w0 + 32768, nmp_w0 + 2*32768, nmp_w0 + 3*32768,
    nmp_w1, nmp_w1 + 16384, nmp_w1 + 2*16384, nmp_w1 + 3*16384 };
  const int KsA[22] = {FEE,128,128,FNN,128,128, 384,384,384,384, 128,128,128,128,
                       256,256,256,256, 128,128,128,128};
  int offs[22]; int tot = 0;
  for (int i = 0; i < 22; ++i){
    pa.j[i].src = srcs[i]; pa.j[i].K = KsA[i];
    offs[i] = tot; tot += ((KsA[i] + 31) & ~31) * HD;
  }
  k_pack<<<tot/256, 256, 0, stream>>>(pa, wpk);

  for (int c = 0; c < 2; ++c){
    float* hout = out + (size_t)c*NN*HD;
    // edge encoding recomputed per chunk (identical result; avoids extra buffer)
    k_encoder<FEE,false><<<EE/64, 256, 0, stream>>>(edge_attr, mve, sve,
        eenc_w0, eenc_b0, wpk + offs[1], eenc_b1, wpk + offs[2], eenc_b2,
        eenc_g, eenc_be, nullptr, e_cur, perm);
    k_encoder<FNN,true><<<NN/64, 256, 0, stream>>>(x + (size_t)c*NN*FNN, mvx, svx,
        nenc_w0, nenc_b0, wpk + offs[4], nenc_b1, wpk + offs[5], nenc_b2,
        nenc_g, nenc_be, hout, hbf, nullptr);
    for (int s = 0; s < SS; ++s){
      k_edge_mlp<<<EE/128, 256, 0, stream>>>(hbf, e_cur,
          wpk + offs[6+s],  emp_b0 + s*HD, wpk + offs[10+s], emp_b1 + s*HD,
          emp_g + s*HD, emp_be + s*HD, ei0p, ei1p);
      k_agg<<<(NN*64 + 255)/256, 256, 0, stream>>>(e_cur, rowst, inv, agg);
      k_node_mlp<<<NN/64, 256, 0, stream>>>(hbf, agg,
          wpk + offs[14+s], nmp_b0 + s*HD, wpk + offs[18+s], nmp_b1 + s*HD,
          nmp_g + s*HD, nmp_be + s*HD, hout);
    }
  }
}

// Round 6
// 1266.196 us; speedup vs baseline: 1.4825x; 1.4825x over previous
//
#include <hip/hip_runtime.h>
#include <math.h>

constexpr int HD  = 128;     // hidden
constexpr int FNN = 6;       // node in-features
constexpr int FEE = 3;       // edge in-features
constexpr int NN  = 40000;   // nodes per chunk
constexpr int EE  = 240000;  // edges
constexpr int SS  = 4;       // mp steps

typedef __bf16 bf16_t;
typedef bf16_t bf16x8 __attribute__((ext_vector_type(8)));
typedef float  f32x4  __attribute__((ext_vector_type(4)));

__device__ __forceinline__ f32x4 mfma16(bf16x8 a, bf16x8 b, f32x4 c){
  return __builtin_amdgcn_mfma_f32_16x16x32_bf16(a, b, c, 0, 0, 0);
}
// fast ELU: exp(v)-1 via v_exp_f32; abs err ~1e-7, invisible after bf16 round
__device__ __forceinline__ float elu(float v){ return v > 0.f ? v : __expf(v) - 1.f; }

// ---------------------------------------------------------------- weight pack
// Packed B-fragment layout per matrix (K padded to mult of 32):
//   flat = ((kt*4 + g)*128 + c)*8 + j   <->   element W[kt*32 + g*8 + j][c]
struct PackJob { const float* src; int K; };
struct PackArgs { PackJob j[22]; };

__global__ void __launch_bounds__(256) k_pack(PackArgs pa, bf16_t* __restrict__ dst){
  int gid = blockIdx.x*256 + threadIdx.x;
  int base = 0;
  #pragma unroll 1
  for (int i = 0; i < 22; ++i){
    int Kp = (pa.j[i].K + 31) & ~31;
    int sz = Kp * HD;
    if (gid < base + sz){
      int idx = gid - base;
      int jj = idx & 7, c = (idx >> 3) & 127, gi = idx >> 10;
      int g = gi & 3, kt = gi >> 2;
      int k = kt*32 + g*8 + jj;
      float v = (k < pa.j[i].K) ? pa.j[i].src[(size_t)k*HD + c] : 0.f;
      dst[base + idx] = (bf16_t)v;
      return;
    }
    base += sz;
  }
}

// ---------------------------------------------------------------- CSR build
__global__ void k_cnt(const int* __restrict__ ei1, int* __restrict__ cnt){
  int t = blockIdx.x*blockDim.x + threadIdx.x;
  if (t < EE) atomicAdd(cnt + ei1[t], 1);
}

__global__ void __launch_bounds__(1024) k_scan(const int* __restrict__ cnt,
    int* __restrict__ rowstart, int* __restrict__ cursor, float* __restrict__ inv){
  __shared__ int sdata[1024];
  __shared__ int carry_s;
  if (threadIdx.x == 0) carry_s = 0;
  __syncthreads();
  for (int base = 0; base < NN; base += 1024){
    int i = base + (int)threadIdx.x;
    int orig = (i < NN) ? cnt[i] : 0;
    sdata[threadIdx.x] = orig;
    __syncthreads();
    #pragma unroll
    for (int ofs = 1; ofs < 1024; ofs <<= 1){
      int t = (threadIdx.x >= (unsigned)ofs) ? sdata[threadIdx.x - ofs] : 0;
      __syncthreads();
      sdata[threadIdx.x] += t;
      __syncthreads();
    }
    int incl = sdata[threadIdx.x];
    int carry = carry_s;
    if (i < NN){
      int start = carry + incl - orig;
      rowstart[i] = start;
      cursor[i]   = start;
      inv[i] = 1.f / fmaxf((float)orig, 1.f);
    }
    __syncthreads();
    if (threadIdx.x == 1023) carry_s = carry + incl;
    __syncthreads();
  }
  if (threadIdx.x == 0) rowstart[NN] = carry_s;
}

__global__ void k_fill(const int* __restrict__ ei0, const int* __restrict__ ei1,
                       int* __restrict__ cursor, int* __restrict__ perm,
                       int2* __restrict__ eidx2){
  int t = blockIdx.x*blockDim.x + threadIdx.x;
  if (t < EE){
    int n1 = ei1[t];
    int pos = atomicAdd(cursor + n1, 1);
    perm[pos] = t;
    int2 v; v.x = ei0[t]; v.y = n1;
    eidx2[pos] = v;
  }
}

// ---------------------------------------------------------------- segment-sum agg
// edges target-sorted; 16 lanes per node, bf16x8 (16B) loads; f32 accum;
// bf16 out with 1/cnt fused
__global__ void __launch_bounds__(256) k_agg(const bf16_t* __restrict__ e,
    const int* __restrict__ rowstart, const float* __restrict__ inv,
    bf16_t* __restrict__ agg){
  int gid = blockIdx.x*256 + (int)threadIdx.x;
  int node = gid >> 4, li = gid & 15;
  if (node >= NN) return;
  int s = rowstart[node], t = rowstart[node+1];
  float a[8] = {0,0,0,0,0,0,0,0};
  for (int ed = s; ed < t; ++ed){
    bf16x8 v = *(const bf16x8*)(e + (size_t)ed*HD + li*8);
    #pragma unroll
    for (int i = 0; i < 8; ++i) a[i] += (float)v[i];
  }
  float sc = inv[node];
  bf16x8 o;
  #pragma unroll
  for (int i = 0; i < 8; ++i) o[i] = (bf16_t)(a[i]*sc);
  *(bf16x8*)(agg + (size_t)node*HD + li*8) = o;
}

// ---------------------------------------------------------------- encoder
// 3-layer MLP (scalar K=FIN layer, then 2 MFMA layers) + LayerNorm.
// Always writes bf16 outb; if ISNODE also writes fp32 outf.
// If perm != nullptr, input row `row` is read from xin[perm[row]] (edge case).
template<int FIN, bool ISNODE>
__global__ void __launch_bounds__(256) k_encoder(
    const float* __restrict__ xin, const float* __restrict__ mv, const float* __restrict__ sv,
    const float* __restrict__ w0,  const float* __restrict__ b0,
    const bf16_t* __restrict__ W1p, const float* __restrict__ b1,
    const bf16_t* __restrict__ W2p, const float* __restrict__ b2,
    const float* __restrict__ gg,  const float* __restrict__ bb,
    float* __restrict__ outf, bf16_t* __restrict__ outb,
    const int* __restrict__ perm)
{
  __shared__ bf16_t z0s[4][16][136];
  __shared__ bf16_t z1s[4][16][136];
  const int tid = threadIdx.x;
  const int w = tid >> 6, l = tid & 63, r = l & 15, grp = l >> 4;
  const int rowbase = blockIdx.x*64 + w*16;
  const int row = rowbase + r;
  const int src = perm ? perm[row] : row;

  float xn[FIN];
  #pragma unroll
  for (int f = 0; f < FIN; ++f) xn[f] = (xin[(size_t)src*FIN + f] - mv[f]) / sv[f];
  #pragma unroll
  for (int q = 0; q < 32; ++q){
    int c = grp*32 + q;
    float a = b0[c];
    #pragma unroll
    for (int f = 0; f < FIN; ++f) a += xn[f] * w0[f*HD + c];
    z0s[w][r][c] = (bf16_t)elu(a);
  }
  __syncthreads();

  bf16x8 a1[4];
  #pragma unroll
  for (int kt = 0; kt < 4; ++kt) a1[kt] = *(const bf16x8*)&z0s[w][r][kt*32 + grp*8];
  #pragma unroll
  for (int nt = 0; nt < 8; ++nt){
    int c = nt*16 + r;
    float bv = b1[c];
    f32x4 acc = {bv, bv, bv, bv};
    #pragma unroll
    for (int kt = 0; kt < 4; ++kt){
      bf16x8 bfr = *(const bf16x8*)(W1p + ((kt*4 + grp)*HD + c)*8);
      acc = mfma16(a1[kt], bfr, acc);
    }
    #pragma unroll
    for (int i = 0; i < 4; ++i) z1s[w][grp*4 + i][c] = (bf16_t)elu(acc[i]);
  }
  __syncthreads();

  bf16x8 a2[4];
  #pragma unroll
  for (int kt = 0; kt < 4; ++kt) a2[kt] = *(const bf16x8*)&z1s[w][r][kt*32 + grp*8];
  f32x4 et[8];
  #pragma unroll
  for (int nt = 0; nt < 8; ++nt){
    int c = nt*16 + r;
    float bv = b2[c];
    f32x4 acc = {bv, bv, bv, bv};
    #pragma unroll
    for (int kt = 0; kt < 4; ++kt){
      bf16x8 bfr = *(const bf16x8*)(W2p + ((kt*4 + grp)*HD + c)*8);
      acc = mfma16(a2[kt], bfr, acc);
    }
    et[nt] = acc;
  }

  f32x4 s = {0,0,0,0}, sq = {0,0,0,0};
  #pragma unroll
  for (int nt = 0; nt < 8; ++nt)
    #pragma unroll
    for (int i = 0; i < 4; ++i){ float v = et[nt][i]; s[i] += v; sq[i] += v*v; }
  #pragma unroll
  for (int m = 1; m < 16; m <<= 1)
    #pragma unroll
    for (int i = 0; i < 4; ++i){ s[i] += __shfl_xor(s[i], m, 64); sq[i] += __shfl_xor(sq[i], m, 64); }
  f32x4 mean, rstd;
  #pragma unroll
  for (int i = 0; i < 4; ++i){
    float mu = s[i] * (1.f/HD);
    float va = sq[i] * (1.f/HD) - mu*mu;
    mean[i] = mu; rstd[i] = rsqrtf(va + 1e-5f);
  }
  #pragma unroll
  for (int nt = 0; nt < 8; ++nt){
    int c = nt*16 + r;
    float gv = gg[c], bv = bb[c];
    #pragma unroll
    for (int i = 0; i < 4; ++i){
      float o = (et[nt][i] - mean[i]) * rstd[i] * gv + bv;
      size_t oidx = (size_t)(rowbase + grp*4 + i)*HD + c;
      outb[oidx] = (bf16_t)o;
      if constexpr (ISNODE) outf[oidx] = o;
    }
  }
}

// ---------------------------------------------------------------- edge MLP step
// e_out = LN(e_in + MLP2(ELU(MLP1(concat[h[ei0], h[ei1], e_in]))))
// R4-proven structure: 4 waves x 16 rows. When e_in==e_out (in-place), each
// wave touches only its own 16 rows and reads precede writes -> safe.
__global__ void __launch_bounds__(256) k_edge_mlp(
    const bf16_t* __restrict__ hbf,
    const bf16_t* e_in, bf16_t* e_out,
    const bf16_t* __restrict__ W0p, const float* __restrict__ b0,
    const bf16_t* __restrict__ W1p, const float* __restrict__ b1,
    const float* __restrict__ gg,  const float* __restrict__ bb,
    const int2* __restrict__ eidx2)
{
  __shared__ bf16_t z1s[4][16][136];
  const int tid = threadIdx.x;
  const int w = tid >> 6, l = tid & 63, r = l & 15, grp = l >> 4;
  const int rowbase = blockIdx.x*64 + w*16;
  const int row = rowbase + r;
  const int2 nn = eidx2[row];

  bf16x8 afr[12];
  #pragma unroll
  for (int kt = 0; kt < 4; ++kt)
    afr[kt] = *(const bf16x8*)(hbf + (size_t)nn.x*HD + kt*32 + grp*8);
  #pragma unroll
  for (int kt = 0; kt < 4; ++kt)
    afr[4+kt] = *(const bf16x8*)(hbf + (size_t)nn.y*HD + kt*32 + grp*8);
  #pragma unroll
  for (int kt = 0; kt < 4; ++kt)
    afr[8+kt] = *(const bf16x8*)(e_in + (size_t)row*HD + kt*32 + grp*8);

  #pragma unroll
  for (int nt = 0; nt < 8; ++nt){
    int c = nt*16 + r;
    float bv = b0[c];
    f32x4 acc = {bv, bv, bv, bv};
    #pragma unroll
    for (int kt = 0; kt < 12; ++kt){
      bf16x8 bfr = *(const bf16x8*)(W0p + ((kt*4 + grp)*HD + c)*8);
      acc = mfma16(afr[kt], bfr, acc);
    }
    #pragma unroll
    for (int i = 0; i < 4; ++i) z1s[w][grp*4 + i][c] = (bf16_t)elu(acc[i]);
  }
  __syncthreads();

  bf16x8 a2[4];
  #pragma unroll
  for (int kt = 0; kt < 4; ++kt) a2[kt] = *(const bf16x8*)&z1s[w][r][kt*32 + grp*8];
  f32x4 et[8];
  #pragma unroll
  for (int nt = 0; nt < 8; ++nt){
    int c = nt*16 + r;
    float bv = b1[c];
    f32x4 acc = {bv, bv, bv, bv};
    #pragma unroll
    for (int kt = 0; kt < 4; ++kt){
      bf16x8 bfr = *(const bf16x8*)(W1p + ((kt*4 + grp)*HD + c)*8);
      acc = mfma16(a2[kt], bfr, acc);
    }
    et[nt] = acc;
  }

  // residual + LN (rows this lane owns: rowbase + grp*4 + i, col c)
  f32x4 s = {0,0,0,0}, sq = {0,0,0,0};
  #pragma unroll
  for (int nt = 0; nt < 8; ++nt){
    int c = nt*16 + r;
    #pragma unroll
    for (int i = 0; i < 4; ++i){
      float v = et[nt][i] + (float)e_in[(size_t)(rowbase + grp*4 + i)*HD + c];
      et[nt][i] = v; s[i] += v; sq[i] += v*v;
    }
  }
  #pragma unroll
  for (int m = 1; m < 16; m <<= 1)
    #pragma unroll
    for (int i = 0; i < 4; ++i){ s[i] += __shfl_xor(s[i], m, 64); sq[i] += __shfl_xor(sq[i], m, 64); }
  f32x4 mean, rstd;
  #pragma unroll
  for (int i = 0; i < 4; ++i){
    float mu = s[i] * (1.f/HD);
    float va = sq[i] * (1.f/HD) - mu*mu;
    mean[i] = mu; rstd[i] = rsqrtf(va + 1e-5f);
  }
  #pragma unroll
  for (int nt = 0; nt < 8; ++nt){
    int c = nt*16 + r;
    float gv = gg[c], bv = bb[c];
    #pragma unroll
    for (int i = 0; i < 4; ++i)
      e_out[(size_t)(rowbase + grp*4 + i)*HD + c] =
          (bf16_t)((et[nt][i] - mean[i]) * rstd[i] * gv + bv);
  }
}

// ---------------------------------------------------------------- node MLP step
// h = LN(h + MLP2(ELU(MLP1(concat[h, agg]))));  agg is bf16, pre-scaled by 1/cnt
__global__ void __launch_bounds__(256) k_node_mlp(
    bf16_t* hbf, const bf16_t* __restrict__ agg,
    const bf16_t* __restrict__ W0p, const float* __restrict__ b0,
    const bf16_t* __restrict__ W1p, const float* __restrict__ b1,
    const float* __restrict__ gg,  const float* __restrict__ bb,
    float* hout)
{
  __shared__ bf16_t z1s[4][16][136];
  const int tid = threadIdx.x;
  const int w = tid >> 6, l = tid & 63, r = l & 15, grp = l >> 4;
  const int rowbase = blockIdx.x*64 + w*16;
  const int row = rowbase + r;

  bf16x8 afr[8];
  #pragma unroll
  for (int kt = 0; kt < 4; ++kt)
    afr[kt] = *(const bf16x8*)(hbf + (size_t)row*HD + kt*32 + grp*8);
  #pragma unroll
  for (int kt = 0; kt < 4; ++kt)
    afr[4+kt] = *(const bf16x8*)(agg + (size_t)row*HD + kt*32 + grp*8);

  #pragma unroll
  for (int nt = 0; nt < 8; ++nt){
    int c = nt*16 + r;
    float bv = b0[c];
    f32x4 acc = {bv, bv, bv, bv};
    #pragma unroll
    for (int kt = 0; kt < 8; ++kt){
      bf16x8 bfr = *(const bf16x8*)(W0p + ((kt*4 + grp)*HD + c)*8);
      acc = mfma16(afr[kt], bfr, acc);
    }
    #pragma unroll
    for (int i = 0; i < 4; ++i) z1s[w][grp*4 + i][c] = (bf16_t)elu(acc[i]);
  }
  __syncthreads();

  bf16x8 a2[4];
  #pragma unroll
  for (int kt = 0; kt < 4; ++kt) a2[kt] = *(const bf16x8*)&z1s[w][r][kt*32 + grp*8];
  f32x4 et[8];
  #pragma unroll
  for (int nt = 0; nt < 8; ++nt){
    int c = nt*16 + r;
    float bv = b1[c];
    f32x4 acc = {bv, bv, bv, bv};
    #pragma unroll
    for (int kt = 0; kt < 4; ++kt){
      bf16x8 bfr = *(const bf16x8*)(W1p + ((kt*4 + grp)*HD + c)*8);
      acc = mfma16(a2[kt], bfr, acc);
    }
    et[nt] = acc;
  }

  f32x4 s = {0,0,0,0}, sq = {0,0,0,0};
  #pragma unroll
  for (int nt = 0; nt < 8; ++nt){
    int c = nt*16 + r;
    #pragma unroll
    for (int i = 0; i < 4; ++i){
      float v = et[nt][i] + hout[(size_t)(rowbase + grp*4 + i)*HD + c];
      et[nt][i] = v; s[i] += v; sq[i] += v*v;
    }
  }
  #pragma unroll
  for (int m = 1; m < 16; m <<= 1)
    #pragma unroll
    for (int i = 0; i < 4; ++i){ s[i] += __shfl_xor(s[i], m, 64); sq[i] += __shfl_xor(sq[i], m, 64); }
  f32x4 mean, rstd;
  #pragma unroll
  for (int i = 0; i < 4; ++i){
    float mu = s[i] * (1.f/HD);
    float va = sq[i] * (1.f/HD) - mu*mu;
    mean[i] = mu; rstd[i] = rsqrtf(va + 1e-5f);
  }
  #pragma unroll
  for (int nt = 0; nt < 8; ++nt){
    int c = nt*16 + r;
    float gv = gg[c], bv = bb[c];
    #pragma unroll
    for (int i = 0; i < 4; ++i){
      float o = (et[nt][i] - mean[i]) * rstd[i] * gv + bv;
      size_t oidx = (size_t)(rowbase + grp*4 + i)*HD + c;
      hout[oidx] = o;
      hbf[oidx]  = (bf16_t)o;
    }
  }
}

// ---------------------------------------------------------------- host
extern "C" void kernel_launch(void* const* d_in, const int* in_sizes, int n_in,
                              void* d_out, int out_size, void* d_ws, size_t ws_size,
                              hipStream_t stream)
{
  (void)in_sizes; (void)n_in; (void)out_size; (void)ws_size;
  const float* x         = (const float*)d_in[0];
  const float* edge_attr = (const float*)d_in[1];
  const float* mvx = (const float*)d_in[2];
  const float* svx = (const float*)d_in[3];
  const float* mve = (const float*)d_in[4];
  const float* sve = (const float*)d_in[5];
  const float* nenc_w0 = (const float*)d_in[6];
  const float* nenc_b0 = (const float*)d_in[7];
  const float* nenc_w1 = (const float*)d_in[8];
  const float* nenc_b1 = (const float*)d_in[9];
  const float* nenc_w2 = (const float*)d_in[10];
  const float* nenc_b2 = (const float*)d_in[11];
  const float* nenc_g  = (const float*)d_in[12];
  const float* nenc_be = (const float*)d_in[13];
  const float* eenc_w0 = (const float*)d_in[14];
  const float* eenc_b0 = (const float*)d_in[15];
  const float* eenc_w1 = (const float*)d_in[16];
  const float* eenc_b1 = (const float*)d_in[17];
  const float* eenc_w2 = (const float*)d_in[18];
  const float* eenc_b2 = (const float*)d_in[19];
  const float* eenc_g  = (const float*)d_in[20];
  const float* eenc_be = (const float*)d_in[21];
  const float* emp_w0 = (const float*)d_in[22];
  const float* emp_b0 = (const float*)d_in[23];
  const float* emp_w1 = (const float*)d_in[24];
  const float* emp_b1 = (const float*)d_in[25];
  const float* emp_g  = (const float*)d_in[26];
  const float* emp_be = (const float*)d_in[27];
  const float* nmp_w0 = (const float*)d_in[28];
  const float* nmp_b0 = (const float*)d_in[29];
  const float* nmp_w1 = (const float*)d_in[30];
  const float* nmp_b1 = (const float*)d_in[31];
  const float* nmp_g  = (const float*)d_in[32];
  const float* nmp_be = (const float*)d_in[33];
  const int* eidx = (const int*)d_in[34];
  const int* ei0 = eidx;
  const int* ei1 = eidx + EE;
  float* out = (float*)d_out;

  // workspace carve-up (all 16B-aligned); total ~148 MB
  char* ws = (char*)d_ws;
  size_t off = 0;
  bf16_t* e_cur = (bf16_t*)(ws + off); off += (size_t)EE*HD*2;
  bf16_t* e0    = (bf16_t*)(ws + off); off += (size_t)EE*HD*2;
  bf16_t* hbf   = (bf16_t*)(ws + off); off += (size_t)NN*HD*2;
  bf16_t* agg   = (bf16_t*)(ws + off); size_t agg_off = off; off += (size_t)NN*HD*2;
  float*  inv   = (float*)(ws + off);  off += (size_t)NN*4;
  int*    rowst = (int*)(ws + off);    off += (size_t)(NN+1)*4 + 12;  // keep 16B align
  int*    perm  = (int*)(ws + off);    off += (size_t)EE*4;
  int2*   eidx2 = (int2*)(ws + off);   off += (size_t)EE*8;
  bf16_t* wpk   = (bf16_t*)(ws + off);
  // CSR build scratch lives inside agg (only used before first k_agg)
  int*    cnt_i = (int*)(ws + agg_off);
  int*    curs  = (int*)(ws + agg_off + (size_t)NN*4);

  // ---- CSR build (target-sorted edge permutation)
  hipMemsetAsync(cnt_i, 0, NN*sizeof(int), stream);
  k_cnt<<<(EE + 255)/256, 256, 0, stream>>>(ei1, cnt_i);
  k_scan<<<1, 1024, 0, stream>>>(cnt_i, rowst, curs, inv);
  k_fill<<<(EE + 255)/256, 256, 0, stream>>>(ei0, ei1, curs, perm, eidx2);

  // ---- weight packing
  PackArgs pa;
  const float* srcs[22] = {
    eenc_w0, eenc_w1, eenc_w2, nenc_w0, nenc_w1, nenc_w2,
    emp_w0, emp_w0 + 49152, emp_w0 + 2*49152, emp_w0 + 3*49152,
    emp_w1, emp_w1 + 16384, emp_w1 + 2*16384, emp_w1 + 3*16384,
    nmp_w0, nmp_w0 + 32768, nmp_w0 + 2*32768, nmp_w0 + 3*32768,
    nmp_w1, nmp_w1 + 16384, nmp_w1 + 2*16384, nmp_w1 + 3*16384 };
  const int KsA[22] = {FEE,128,128,FNN,128,128, 384,384,384,384, 128,128,128,128,
                       256,256,256,256, 128,128,128,128};
  int offs[22]; int tot = 0;
  for (int i = 0; i < 22; ++i){
    pa.j[i].src = srcs[i]; pa.j[i].K = KsA[i];
    offs[i] = tot; tot += ((KsA[i] + 31) & ~31) * HD;
  }
  k_pack<<<tot/256, 256, 0, stream>>>(pa, wpk);

  // ---- edge encoder ONCE (chunk-invariant), into e0 (permuted edge order)
  k_encoder<FEE,false><<<EE/64, 256, 0, stream>>>(edge_attr, mve, sve,
      eenc_w0, eenc_b0, wpk + offs[1], eenc_b1, wpk + offs[2], eenc_b2,
      eenc_g, eenc_be, nullptr, e0, perm);

  for (int c = 0; c < 2; ++c){
    float* hout = out + (size_t)c*NN*HD;
    k_encoder<FNN,true><<<NN/64, 256, 0, stream>>>(x + (size_t)c*NN*FNN, mvx, svx,
        nenc_w0, nenc_b0, wpk + offs[4], nenc_b1, wpk + offs[5], nenc_b2,
        nenc_g, nenc_be, hout, hbf, nullptr);
    for (int s = 0; s < SS; ++s){
      const bf16_t* e_in = (s == 0) ? e0 : e_cur;   // step 0 reads cached e0
      k_edge_mlp<<<EE/64, 256, 0, stream>>>(hbf, e_in, e_cur,
          wpk + offs[6+s],  emp_b0 + s*HD, wpk + offs[10+s], emp_b1 + s*HD,
          emp_g + s*HD, emp_be + s*HD, eidx2);
      k_agg<<<(NN*16 + 255)/256, 256, 0, stream>>>(e_cur, rowst, inv, agg);
      k_node_mlp<<<NN/64, 256, 0, stream>>>(hbf, agg,
          wpk + offs[14+s], nmp_b0 + s*HD, wpk + offs[18+s], nmp_b1 + s*HD,
          nmp_g + s*HD, nmp_be + s*HD, hout);
    }
  }
}